// Round 11
// baseline (243.457 us; speedup 1.0000x reference)
//
#include <hip/hip_runtime.h>
#include <hip/hip_bf16.h>

typedef __attribute__((ext_vector_type(8))) short bf16x8;
typedef __attribute__((ext_vector_type(4))) short s16x4;
typedef __attribute__((ext_vector_type(4))) float f32x4;
typedef __attribute__((ext_vector_type(4))) float float4v;

static __device__ __forceinline__ unsigned short f2b(float f) {
  unsigned int u = __builtin_bit_cast(unsigned int, f);
  u += 0x7fffu + ((u >> 16) & 1u);
  return (unsigned short)(u >> 16);
}
static __device__ __forceinline__ float b2f(unsigned short s) {
  unsigned int u = ((unsigned int)s) << 16;
  return __builtin_bit_cast(float, u);
}
// fast silu/softplus on TRANS pipe; bf16-accurate
static __device__ __forceinline__ float fsilu(float x) {
  float e = __builtin_amdgcn_exp2f(-1.44269504f * x);
  return x * __builtin_amdgcn_rcpf(1.f + e);
}
static __device__ __forceinline__ float fsoftplus(float a) {
  if (a > 20.f) return a;
  float t = __builtin_amdgcn_exp2f(1.44269504f * a);
  return 0.69314718f * __builtin_amdgcn_logf(1.f + t);
}
// async global->LDS, 16B/lane; dest wave-uniform base + lane*16,
// source per-lane (enables source-side swizzling, rule #21)
static __device__ __forceinline__ void gl16(const void* g, void* l) {
  __builtin_amdgcn_global_load_lds(
      (const __attribute__((address_space(1))) unsigned int*)g,
      (__attribute__((address_space(3))) unsigned int*)l, 16, 0, 0);
}
template <int N>
static __device__ __forceinline__ void waitv() {
  if constexpr (N == 0) asm volatile("s_waitcnt vmcnt(0)" ::: "memory");
  else if constexpr (N == 2) asm volatile("s_waitcnt vmcnt(2)" ::: "memory");
  else if constexpr (N == 3) asm volatile("s_waitcnt vmcnt(3)" ::: "memory");
  else if constexpr (N == 4) asm volatile("s_waitcnt vmcnt(4)" ::: "memory");
  else if constexpr (N == 6) asm volatile("s_waitcnt vmcnt(6)" ::: "memory");
  else if constexpr (N == 8) asm volatile("s_waitcnt vmcnt(8)" ::: "memory");
}
static __device__ __forceinline__ void lgkm_bar() {
  asm volatile("s_waitcnt lgkmcnt(0)" ::: "memory");
  __builtin_amdgcn_s_barrier();
}

// ---------------------------------------------------------------------------
// pre-GEMM: C = A @ W^T + bias, bf16 MFMA, fp32 accum. 128x64, BK=32,
// 4 waves, depth-4 ring, counted vmcnt, chunk-XOR swizzle, XCD swizzle.
// ---------------------------------------------------------------------------
template <int TM, int TN>
__global__ __launch_bounds__(256) void gemm_pl(
    const unsigned short* __restrict__ A, const unsigned short* __restrict__ W,
    int N, int K, int GY,
    const float* __restrict__ p0, float* __restrict__ of,
    unsigned short* __restrict__ ob) {
  constexpr int FM = TM / 32, FN = TN / 32;
  constexpr int IA = TM / 64, IW = TN / 64;
  constexpr int LPT = IA + IW;
  __shared__ __align__(16) unsigned short As[4][TM * 32];
  __shared__ __align__(16) unsigned short Ws[4][TN * 32];

  const int t = threadIdx.x, lane = t & 63, wave = t >> 6;
  const int lr = lane & 15;
  const int q = gridDim.x >> 3;
  const int s = (blockIdx.x & 7) * q + (blockIdx.x >> 3);
  const int bm = (s / GY) * TM, bn = (s % GY) * TN;
  const int wr = (wave >> 1) * (TM / 2), wc = (wave & 1) * (TN / 2);

  f32x4 acc[FM][FN];
#pragma unroll
  for (int i = 0; i < FM; ++i)
#pragma unroll
    for (int j = 0; j < FN; ++j) acc[i][j] = (f32x4){0.f, 0.f, 0.f, 0.f};

  const unsigned short* agB =
      A + (long)(bm + wave * (TM / 4) + (lane >> 2)) * K +
      ((lane & 3) ^ ((lane >> 3) & 3)) * 8;
  const unsigned short* wgB =
      W + (long)(bn + wave * (TN / 4) + (lane >> 2)) * K +
      ((lane & 3) ^ ((lane >> 3) & 3)) * 8;

  auto STAGE = [&](int k0, int b) {
#pragma unroll
    for (int j = 0; j < IA; ++j)
      gl16(agB + k0 + (long)j * 16 * K, &As[b][(wave * (TM / 4) + j * 16) * 32]);
#pragma unroll
    for (int j = 0; j < IW; ++j)
      gl16(wgB + k0 + (long)j * 16 * K, &Ws[b][(wave * (TN / 4) + j * 16) * 32]);
  };

  auto COMPUTE = [&](int b) {
    bf16x8 af[FM], bg[FN];
    const int sw = ((lane >> 4) ^ ((lane >> 1) & 3)) * 8;
#pragma unroll
    for (int m = 0; m < FM; ++m)
      af[m] = *(const bf16x8*)&As[b][(wr + m * 16 + lr) * 32 + sw];
#pragma unroll
    for (int n = 0; n < FN; ++n)
      bg[n] = *(const bf16x8*)&Ws[b][(wc + n * 16 + lr) * 32 + sw];
    __builtin_amdgcn_s_setprio(1);
#pragma unroll
    for (int m = 0; m < FM; ++m)
#pragma unroll
      for (int n = 0; n < FN; ++n)
        acc[m][n] = __builtin_amdgcn_mfma_f32_16x16x32_bf16(af[m], bg[n],
                                                            acc[m][n], 0, 0, 0);
    __builtin_amdgcn_s_setprio(0);
  };

  const int NT = K >> 5;
  STAGE(0, 0);
  STAGE(32, 1);
  for (int tt = 0; tt < NT; ++tt) {
    if (tt + 2 < NT) {
      STAGE((tt + 2) << 5, (tt + 2) & 3);
      waitv<2 * LPT>();
    } else if (tt + 1 < NT) {
      waitv<LPT>();
    } else {
      waitv<0>();
    }
    __builtin_amdgcn_s_barrier();
    COMPUTE(tt & 3);
    __builtin_amdgcn_sched_barrier(0);
  }

  const int m0 = bm + wr + (lane >> 4) * 4;
  const int n0 = bn + wc + lr;
#pragma unroll
  for (int mi = 0; mi < FM; ++mi)
#pragma unroll
    for (int ni = 0; ni < FN; ++ni) {
      const int n = n0 + ni * 16;
#pragma unroll
      for (int r = 0; r < 4; ++r) {
        const int m = m0 + mi * 16 + r;
        float v = acc[mi][ni][r] + p0[n];
        of[(long)m * N + n] = v;
        ob[(long)m * N + n] = f2b(v);
      }
    }
}

// ---------------------------------------------------------------------------
// mamba5: 5 Mamba blocks fused, grid 256 x 512thr, 32 rows/block, h resident.
// Register-blocked: each wave owns 32M x 32N (acc[2][2], 8 MFMA per tt,
// reads/MFMA = 1.0). Tiles [256N x 64K] = 32KB, Ring = 2 x 32KB, depth-1
// stage-after-barrier (slot (tt+1)&1 = the slot computed at tt-1, whose
// reads completed before barrier(tt)). All loops unrolled -> swizzle offsets
// compile-time. No global loads inside loops (conv tap3 folded into inwb;
// cb/dtb/D in Par LDS). L=1: conv = tap3*xi+cb; scan -> y=xi*(dt*BC+D)*silu(z).
// SMEM (shorts): XiL[0,16384) SzL[16384,32768) Ring[32768,65536)
//   HLr[65536,73728) Dxl@73728(32x68 f32) BCl@78080 Par@78144(1536 f32)
// ---------------------------------------------------------------------------
__global__ __launch_bounds__(512) void mamba5(
    const unsigned short* __restrict__ hb0, const float* __restrict__ h0,
    const unsigned short* __restrict__ inwb,
    const unsigned short* __restrict__ xwpb,
    const unsigned short* __restrict__ dtwpb,
    const unsigned short* __restrict__ owb,
    const float* __restrict__ conv_b, const float* __restrict__ dt_b,
    const float* __restrict__ Dp, float* __restrict__ hout) {
  __shared__ __align__(16) unsigned short SMEM[81216];
  unsigned short* XiL = SMEM;
  unsigned short* SzL = SMEM + 16384;
  unsigned short* Ring = SMEM + 32768;
  unsigned short* HLr = SMEM + 65536;
  float* Dxl = (float*)(SMEM + 73728);
  float* BCl = (float*)(SMEM + 78080);
  float* Par = (float*)(SMEM + 78144);

  const int t = threadIdx.x, lane = t & 63, w = t >> 6;
  const int lr = lane & 15, lg = lane >> 4;
  const int bm = blockIdx.x * 32;
  const int m04 = lg * 4;              // frag row base within 16-row block
  const int srow8 = lane >> 3;         // staging: row within 8-row group
  const int sc = (lane & 7) ^ srow8;   // staging: pre-swizzled src chunk
  const int wc32 = w * 32;             // wave's 32-col base

  // ---- init: h bf16 -> HLr (chunk-swizzled); fp32 residual -> regs ----
#pragma unroll
  for (int j = 0; j < 2; ++j) {
    const int i = w * 2 + j;
    const int row = 2 * i + (lane >> 5);
    const int c = (lane & 31) ^ (row & 7);
    gl16(hb0 + (long)(bm + row) * 256 + c * 8, HLr + i * 512);
  }
  float hres[2][2][4];
#pragma unroll
  for (int fm = 0; fm < 2; ++fm)
#pragma unroll
    for (int n = 0; n < 2; ++n)
#pragma unroll
      for (int r = 0; r < 4; ++r)
        hres[fm][n][r] =
            h0[(long)(bm + fm * 16 + m04 + r) * 256 + wc32 + n * 16 + lr];
  waitv<0>();
  __builtin_amdgcn_s_barrier();

  for (int blk = 0; blk < 5; ++blk) {
    const unsigned short* inw = inwb + (long)blk * 1024 * 256;
    const unsigned short* xwp = xwpb + (long)blk * 64 * 512;
    const unsigned short* dtwp = dtwpb + (long)blk * 512 * 32;
    const unsigned short* ow = owb + (long)blk * 256 * 512;
    const float* cbv = conv_b + blk * 512;
    const float* dtbv = dt_b + blk * 512;
    const float* Dv = Dp + blk * 512;

    // ================= P1: xz = h @ in_w'^T (conv-folded) =================
    auto STAGE1 = [&](int p, int qq, int slot) {
#pragma unroll
      for (int j = 0; j < 4; ++j) {
        const int u = w * 4 + j;  // 32 gl16/tile, 8 rows (128B) each
        gl16(inw + (long)(p * 256 + u * 8 + srow8) * 256 + qq * 64 + sc * 8,
             Ring + slot * 16384 + u * 512);
      }
    };
    if (w < 6) {  // params -> Par (drained with tile0 at first waitv)
      const float* ps = (w < 2) ? cbv + (w & 1) * 256
                      : (w < 4) ? dtbv + (w & 1) * 256
                                : Dv + (w & 1) * 256;
      gl16(ps + lane * 4, (unsigned short*)Par + w * 512);
    }
    STAGE1(0, 0, 0);
    f32x4 acc1[2][2];
#pragma unroll
    for (int p = 0; p < 4; ++p) {
#pragma unroll
      for (int qq = 0; qq < 4; ++qq) {
        waitv<0>();
        __builtin_amdgcn_s_barrier();
        if (qq < 3) STAGE1(p, qq + 1, (qq + 1) & 1);
        else if (p < 3) STAGE1(p + 1, 0, 0);
        __builtin_amdgcn_sched_barrier(0);
        if (qq == 0) {
#pragma unroll
          for (int n = 0; n < 2; ++n) {
            const int c = p * 256 + wc32 + n * 16 + lr;
            const float cb = (p < 2) ? Par[c] : 0.f;
            acc1[0][n] = (f32x4){cb, cb, cb, cb};
            acc1[1][n] = acc1[0][n];
          }
        }
        const unsigned short* Bs = Ring + (qq & 1) * 16384;
        bf16x8 af[2][2], bg[2][2];
#pragma unroll
        for (int kc = 0; kc < 2; ++kc) {
          const int e = ((kc * 4 + lg) ^ (lr & 7)) * 8;
#pragma unroll
          for (int fm = 0; fm < 2; ++fm)
            af[fm][kc] =
                *(const bf16x8*)&HLr[(fm * 16 + lr) * 256 + qq * 64 + e];
#pragma unroll
          for (int n = 0; n < 2; ++n)
            bg[n][kc] = *(const bf16x8*)&Bs[(wc32 + n * 16 + lr) * 64 + e];
        }
        __builtin_amdgcn_s_setprio(1);
#pragma unroll
        for (int kc = 0; kc < 2; ++kc)
#pragma unroll
          for (int fm = 0; fm < 2; ++fm)
#pragma unroll
            for (int n = 0; n < 2; ++n)
              acc1[fm][n] = __builtin_amdgcn_mfma_f32_16x16x32_bf16(
                  af[fm][kc], bg[n][kc], acc1[fm][n], 0, 0, 0);
        __builtin_amdgcn_s_setprio(0);
        if (qq == 3) {
#pragma unroll
          for (int fm = 0; fm < 2; ++fm)
#pragma unroll
            for (int n = 0; n < 2; ++n) {
              const int c = p * 256 + wc32 + n * 16 + lr;
#pragma unroll
              for (int r = 0; r < 4; ++r) {
                const int row = fm * 16 + m04 + r;
                const float v = fsilu(acc1[fm][n][r]);
                if (p < 2)
                  XiL[row * 512 + (((c >> 3) ^ (row & 7)) * 8) + (c & 7)] =
                      f2b(v);
                else
                  SzL[row * 512 + (c - 512)] = f2b(v);
              }
            }
        }
        __builtin_amdgcn_sched_barrier(0);
      }
    }
    lgkm_bar();  // Xi/Sz visible; Ring reads retired

    // ====== P2: xdbl = xi @ xwp^T (xwp 64KB fills both Ring slots) ======
#pragma unroll
    for (int j = 0; j < 8; ++j) {
      const int i = w * 8 + j;  // 64 gl16, 1 row (1KB) each
      gl16(xwp + (long)i * 512 + (lane ^ (i & 7)) * 8, Ring + i * 512);
    }
    waitv<0>();
    __builtin_amdgcn_s_barrier();
    {
      const int fm2 = w & 1, fn2 = w >> 1;
      const int ar = fm2 * 16 + lr, rb = fn2 * 16 + lr;
      f32x4 a2 = {0.f, 0.f, 0.f, 0.f};
      __builtin_amdgcn_s_setprio(1);
#pragma unroll
      for (int kc = 0; kc < 16; ++kc) {
        bf16x8 af = *(const bf16x8*)
            &XiL[ar * 512 + (((kc * 4 + lg) ^ (lr & 7)) * 8)];
        bf16x8 bg = *(const bf16x8*)
            &Ring[rb * 512 + (((kc * 4 + lg) ^ (lr & 7)) * 8)];
        a2 = __builtin_amdgcn_mfma_f32_16x16x32_bf16(af, bg, a2, 0, 0, 0);
      }
      __builtin_amdgcn_s_setprio(0);
#pragma unroll
      for (int r = 0; r < 4; ++r)
        Dxl[(fm2 * 16 + m04 + r) * 68 + fn2 * 16 + lr] = a2[r];
    }
    lgkm_bar();  // Dxl visible; Ring reads retired

    // ===== P4 prologue: dtwp [512x32]=32KB into Ring slot0; overlap with
    // BC + afdt prep =====
#pragma unroll
    for (int j = 0; j < 4; ++j) {
      const int u = w * 4 + j;  // 32 gl16, 16 rows (64B) each
      const int row = u * 16 + (lane >> 2);
      const int c = (lane & 3) ^ (row & 3);
      gl16(dtwp + (long)row * 32 + c * 8, Ring + u * 512);
    }
    if (t < 32) {
      float bc = 0.f;
      const float* dx = &Dxl[t * 68];
#pragma unroll
      for (int s2 = 0; s2 < 16; ++s2) bc += dx[16 + s2] * dx[32 + s2];
      BCl[t] = bc;
    }
    bf16x8 afdt;
    {
      // k 16..31 multiply vs zero-padded dtwp rows: contribute 0
      const float* dx = &Dxl[((w & 1) * 16 + lr) * 68 + lg * 8];
#pragma unroll
      for (int e = 0; e < 8; ++e) afdt[e] = (short)f2b(dx[e]);
    }
    waitv<0>();
    lgkm_bar();  // dtwp + BCl visible

    // ===== P4: dt = softplus(xdbl[:,:16]@dtwp^T + dtb); y (barrier-free) ==
    {
      const int fn4 = w >> 1, m04b = (w & 1) * 16 + m04;
#pragma unroll
      for (int tt = 0; tt < 8; ++tt) {
        const int d = tt * 64 + fn4 * 16 + lr;
        bf16x8 bg = *(const bf16x8*)&Ring[d * 32 + ((lg ^ (d & 3)) * 8)];
        f32x4 da = __builtin_amdgcn_mfma_f32_16x16x32_bf16(
            afdt, bg, (f32x4){0.f, 0.f, 0.f, 0.f}, 0, 0, 0);
        const float dbv = Par[512 + d], dvv = Par[1024 + d];
#pragma unroll
        for (int r = 0; r < 4; ++r) {
          const int row = m04b + r;
          const float dtv = fsoftplus(da[r] + dbv);
          const int xoff = row * 512 + (((d >> 3) ^ (row & 7)) * 8) + (d & 7);
          const float y = b2f(XiL[xoff]) * (dtv * BCl[row] + dvv) *
                          b2f(SzL[row * 512 + d]);
          XiL[xoff] = f2b(y);  // y overwrites xi in place
        }
      }
    }
    lgkm_bar();  // y visible; dtwp reads retired

    // ===== P5: h += y @ ow^T (8 tiles [256N x 64K], ring-2 depth-1) =====
    auto STAGE5 = [&](int tt, int slot) {
#pragma unroll
      for (int j = 0; j < 4; ++j) {
        const int u = w * 4 + j;
        gl16(ow + (long)(u * 8 + srow8) * 512 + tt * 64 + sc * 8,
             Ring + slot * 16384 + u * 512);
      }
    };
    STAGE5(0, 0);
    f32x4 acc5[2][2];
#pragma unroll
    for (int fm = 0; fm < 2; ++fm)
#pragma unroll
      for (int n = 0; n < 2; ++n) acc5[fm][n] = (f32x4){0.f, 0.f, 0.f, 0.f};
#pragma unroll
    for (int tt = 0; tt < 8; ++tt) {
      waitv<0>();
      __builtin_amdgcn_s_barrier();
      if (tt < 7) STAGE5(tt + 1, (tt + 1) & 1);
      __builtin_amdgcn_sched_barrier(0);
      const unsigned short* Bs = Ring + (tt & 1) * 16384;
      bf16x8 af[2][2], bg[2][2];
#pragma unroll
      for (int kc = 0; kc < 2; ++kc) {
        const int e = ((kc * 4 + lg) ^ (lr & 7)) * 8;
#pragma unroll
        for (int fm = 0; fm < 2; ++fm)
          af[fm][kc] =
              *(const bf16x8*)&XiL[(fm * 16 + lr) * 512 + tt * 64 + e];
#pragma unroll
        for (int n = 0; n < 2; ++n)
          bg[n][kc] = *(const bf16x8*)&Bs[(wc32 + n * 16 + lr) * 64 + e];
      }
      __builtin_amdgcn_s_setprio(1);
#pragma unroll
      for (int kc = 0; kc < 2; ++kc)
#pragma unroll
        for (int fm = 0; fm < 2; ++fm)
#pragma unroll
          for (int n = 0; n < 2; ++n)
            acc5[fm][n] = __builtin_amdgcn_mfma_f32_16x16x32_bf16(
                af[fm][kc], bg[n][kc], acc5[fm][n], 0, 0, 0);
      __builtin_amdgcn_s_setprio(0);
      __builtin_amdgcn_sched_barrier(0);
    }
    // epilogue: h += acc; bf16 h -> HLr (swizzled) for next block's P1
#pragma unroll
    for (int fm = 0; fm < 2; ++fm)
#pragma unroll
      for (int n = 0; n < 2; ++n) {
        const int col = wc32 + n * 16 + lr;
#pragma unroll
        for (int r = 0; r < 4; ++r) {
          const int row = fm * 16 + m04 + r;
          const float v = acc5[fm][n][r] + hres[fm][n][r];
          hres[fm][n][r] = v;
          HLr[row * 256 + (((col >> 3) ^ (row & 7)) * 8) + (col & 7)] = f2b(v);
        }
      }
    lgkm_bar();  // new h visible for next blk's P1
  }

  // ---- final h fp32 write for LN+cls ----
#pragma unroll
  for (int fm = 0; fm < 2; ++fm)
#pragma unroll
    for (int n = 0; n < 2; ++n)
#pragma unroll
      for (int r = 0; r < 4; ++r)
        hout[(long)(bm + fm * 16 + m04 + r) * 256 + wc32 + n * 16 + lr] =
            hres[fm][n][r];
}

// x fp32 -> bf16 streaming cast
__global__ __launch_bounds__(256) void castx(const float* __restrict__ s,
                                             unsigned short* __restrict__ d) {
  const int n4 = (8192 * 2048) / 4;
  for (int i = blockIdx.x * 256 + threadIdx.x; i < n4; i += gridDim.x * 256) {
    float4v v = ((const float4v*)s)[i];
    s16x4 o;
    o[0] = (short)f2b(v[0]); o[1] = (short)f2b(v[1]);
    o[2] = (short)f2b(v[2]); o[3] = (short)f2b(v[3]);
    ((s16x4*)d)[i] = o;
  }
}

// weight precast: W_pre -> bf16; in_w -> bf16 with conv tap3 folded into
// rows <512; out_w -> bf16; x_proj -> padded [64x512]; dt_w -> padded [512x32]
__global__ __launch_bounds__(256) void precast(
    const float* __restrict__ wpre, const float* __restrict__ inw,
    const float* __restrict__ ow, const float* __restrict__ xw,
    const float* __restrict__ dtw, const float* __restrict__ cw,
    unsigned short* __restrict__ wpreb, unsigned short* __restrict__ inwb,
    unsigned short* __restrict__ owb, unsigned short* __restrict__ xwpb,
    unsigned short* __restrict__ dtwpb) {
  const int S0 = 524288;         // 256*2048
  const int S1 = S0 + 1310720;   // + 5*1024*256
  const int S2 = S1 + 655360;    // + 5*256*512
  const int S3 = S2 + 163840;    // + 5*64*512
  const int S4 = S3 + 81920;     // + 5*512*32
  int i4 = (blockIdx.x * 256 + threadIdx.x) * 4;
  if (i4 >= S4) return;
  float4v v = {0.f, 0.f, 0.f, 0.f};
  unsigned short* dst;
  if (i4 < S0) {
    v = *(const float4v*)(wpre + i4);
    dst = wpreb + i4;
  } else if (i4 < S1) {
    int o = i4 - S0;
    v = *(const float4v*)(inw + o);
    int b = o >> 18, row = (o >> 8) & 1023;
    if (row < 512) {
      float c3 = cw[(b * 512 + row) * 4 + 3];
      v[0] *= c3; v[1] *= c3; v[2] *= c3; v[3] *= c3;
    }
    dst = inwb + o;
  } else if (i4 < S2) {
    int o = i4 - S1;
    v = *(const float4v*)(ow + o);
    dst = owb + o;
  } else if (i4 < S3) {
    int o = i4 - S2;
    dst = xwpb + o;
    int k = o & 511, j = (o >> 9) & 63, b = o >> 15;
    if (j < 48) v = *(const float4v*)(xw + ((long)(b * 48 + j)) * 512 + k);
  } else {
    int o = i4 - S3;
    dst = dtwpb + o;
    int k = o & 31, dd = o >> 5;
    if (k < 16) v = *(const float4v*)(dtw + (long)dd * 16 + k);
  }
  s16x4 sv;
  sv[0] = (short)f2b(v[0]); sv[1] = (short)f2b(v[1]);
  sv[2] = (short)f2b(v[2]); sv[3] = (short)f2b(v[3]);
  *(s16x4*)dst = sv;
}

// LayerNorm(256) + classifier (8 outputs). One wave per row.
__global__ __launch_bounds__(256) void final_ln_cls(
    const float* __restrict__ h, const float* __restrict__ g,
    const float* __restrict__ be, const float* __restrict__ Wc,
    const float* __restrict__ bc, float* __restrict__ out) {
  const int wave = threadIdx.x >> 6, lane = threadIdx.x & 63;
  const int row = blockIdx.x * 4 + wave;
  const float4v* hr = (const float4v*)(h + (long)row * 256);
  float4v v = hr[lane];
  float s = v[0] + v[1] + v[2] + v[3];
#pragma unroll
  for (int o = 32; o; o >>= 1) s += __shfl_xor(s, o);
  const float mu = s * (1.f / 256.f);
  float d0 = v[0] - mu, d1 = v[1] - mu, d2 = v[2] - mu, d3 = v[3] - mu;
  float qq = d0 * d0 + d1 * d1 + d2 * d2 + d3 * d3;
#pragma unroll
  for (int o = 32; o; o >>= 1) qq += __shfl_xor(qq, o);
  const float rs = rsqrtf(qq * (1.f / 256.f) + 1e-5f);
  const float4v gv = ((const float4v*)g)[lane];
  const float4v bv = ((const float4v*)be)[lane];
  float hn[4];
  hn[0] = d0 * rs * gv[0] + bv[0];
  hn[1] = d1 * rs * gv[1] + bv[1];
  hn[2] = d2 * rs * gv[2] + bv[2];
  hn[3] = d3 * rs * gv[3] + bv[3];
  float lg[8];
#pragma unroll
  for (int o = 0; o < 8; ++o) {
    const float4v wv = ((const float4v*)(Wc + o * 256))[lane];
    float p = hn[0] * wv[0] + hn[1] * wv[1] + hn[2] * wv[2] + hn[3] * wv[3];
#pragma unroll
    for (int x = 32; x; x >>= 1) p += __shfl_xor(p, x);
    lg[o] = p;
  }
  if (lane == 0) {
#pragma unroll
    for (int o = 0; o < 8; ++o) out[(long)row * 8 + o] = lg[o] + bc[o];
  }
}

extern "C" void kernel_launch(void* const* d_in, const int* in_sizes, int n_in,
                              void* d_out, int out_size, void* d_ws,
                              size_t ws_size, hipStream_t stream) {
  const float* x      = (const float*)d_in[0];
  const float* W_pre  = (const float*)d_in[1];
  const float* b_pre  = (const float*)d_in[2];
  const float* in_w   = (const float*)d_in[3];
  const float* conv_w = (const float*)d_in[4];
  const float* conv_b = (const float*)d_in[5];
  const float* x_w    = (const float*)d_in[6];
  const float* dt_w   = (const float*)d_in[7];
  const float* dt_b   = (const float*)d_in[8];
  // d_in[9] = A_log: dead (scan starts from h0=0 and L=1)
  const float* Dp     = (const float*)d_in[10];
  const float* out_w  = (const float*)d_in[11];
  const float* ln_g   = (const float*)d_in[12];
  const float* ln_b   = (const float*)d_in[13];
  const float* W_cls  = (const float*)d_in[14];
  const float* b_cls  = (const float*)d_in[15];
  float* out = (float*)d_out;

  char* w = (char*)d_ws;
  unsigned short* wpreb = (unsigned short*)w; w += 256 * 2048 * 2;
  unsigned short* inwb  = (unsigned short*)w; w += 5 * 1024 * 256 * 2;
  unsigned short* xwpb  = (unsigned short*)w; w += 5 * 64 * 512 * 2;
  unsigned short* owb   = (unsigned short*)w; w += 5 * 256 * 512 * 2;
  unsigned short* dtwpb = (unsigned short*)w; w += 5 * 512 * 32 * 2;
  float*          h     = (float*)w;          w += 8192 * 256 * 4;
  unsigned short* hb    = (unsigned short*)w; w += 8192 * 256 * 2;
  unsigned short* xb    = (unsigned short*)w; w += 8192 * 2048 * 2;

  precast<<<2672, 256, 0, stream>>>(W_pre, in_w, out_w, x_w, dt_w, conv_w,
                                    wpreb, inwb, owb, xwpb, dtwpb);
  castx<<<2048, 256, 0, stream>>>(x, xb);

  // h = x @ W_pre^T + b_pre  (fp32 of + bf16 ob)
  gemm_pl<128, 64><<<256, 256, 0, stream>>>(
      xb, wpreb, 256, 2048, 4, b_pre, h, hb);

  // all 5 Mamba blocks, one persistent kernel, h resident
  mamba5<<<256, 512, 0, stream>>>(hb, h, inwb, xwpb, dtwpb, owb,
                                  conv_b, dt_b, Dp, h);

  final_ln_cls<<<2048, 256, 0, stream>>>(h, ln_g, ln_b, W_cls, b_cls, out);
}

// Round 12
// 216.172 us; speedup vs baseline: 1.1262x; 1.1262x over previous
//
#include <hip/hip_runtime.h>
#include <hip/hip_bf16.h>

typedef __attribute__((ext_vector_type(8))) short bf16x8;
typedef __attribute__((ext_vector_type(4))) short s16x4;
typedef __attribute__((ext_vector_type(4))) float f32x4;
typedef __attribute__((ext_vector_type(4))) float float4v;

static __device__ __forceinline__ unsigned short f2b(float f) {
  unsigned int u = __builtin_bit_cast(unsigned int, f);
  u += 0x7fffu + ((u >> 16) & 1u);
  return (unsigned short)(u >> 16);
}
static __device__ __forceinline__ float b2f(unsigned short s) {
  unsigned int u = ((unsigned int)s) << 16;
  return __builtin_bit_cast(float, u);
}
// fast silu/softplus on TRANS pipe; bf16-accurate
static __device__ __forceinline__ float fsilu(float x) {
  float e = __builtin_amdgcn_exp2f(-1.44269504f * x);
  return x * __builtin_amdgcn_rcpf(1.f + e);
}
static __device__ __forceinline__ float fsoftplus(float a) {
  if (a > 20.f) return a;
  float t = __builtin_amdgcn_exp2f(1.44269504f * a);
  return 0.69314718f * __builtin_amdgcn_logf(1.f + t);
}
// async global->LDS, 16B/lane; dest wave-uniform base + lane*16,
// source per-lane (enables source-side swizzling, rule #21)
static __device__ __forceinline__ void gl16(const void* g, void* l) {
  __builtin_amdgcn_global_load_lds(
      (const __attribute__((address_space(1))) unsigned int*)g,
      (__attribute__((address_space(3))) unsigned int*)l, 16, 0, 0);
}
template <int N>
static __device__ __forceinline__ void waitv() {
  if constexpr (N == 0) asm volatile("s_waitcnt vmcnt(0)" ::: "memory");
  else if constexpr (N == 2) asm volatile("s_waitcnt vmcnt(2)" ::: "memory");
  else if constexpr (N == 3) asm volatile("s_waitcnt vmcnt(3)" ::: "memory");
  else if constexpr (N == 4) asm volatile("s_waitcnt vmcnt(4)" ::: "memory");
  else if constexpr (N == 6) asm volatile("s_waitcnt vmcnt(6)" ::: "memory");
  else if constexpr (N == 8) asm volatile("s_waitcnt vmcnt(8)" ::: "memory");
}
static __device__ __forceinline__ void lgkm_bar() {
  asm volatile("s_waitcnt lgkmcnt(0)" ::: "memory");
  __builtin_amdgcn_s_barrier();
}

// ---------------------------------------------------------------------------
// pre-GEMM: C = A @ W^T + bias, bf16 MFMA, fp32 accum. 128x64, BK=32,
// 4 waves, depth-4 ring, counted vmcnt, chunk-XOR swizzle, XCD swizzle.
// ---------------------------------------------------------------------------
template <int TM, int TN>
__global__ __launch_bounds__(256) void gemm_pl(
    const unsigned short* __restrict__ A, const unsigned short* __restrict__ W,
    int N, int K, int GY,
    const float* __restrict__ p0, float* __restrict__ of,
    unsigned short* __restrict__ ob) {
  constexpr int FM = TM / 32, FN = TN / 32;
  constexpr int IA = TM / 64, IW = TN / 64;
  constexpr int LPT = IA + IW;
  __shared__ __align__(16) unsigned short As[4][TM * 32];
  __shared__ __align__(16) unsigned short Ws[4][TN * 32];

  const int t = threadIdx.x, lane = t & 63, wave = t >> 6;
  const int lr = lane & 15;
  const int q = gridDim.x >> 3;
  const int s = (blockIdx.x & 7) * q + (blockIdx.x >> 3);
  const int bm = (s / GY) * TM, bn = (s % GY) * TN;
  const int wr = (wave >> 1) * (TM / 2), wc = (wave & 1) * (TN / 2);

  f32x4 acc[FM][FN];
#pragma unroll
  for (int i = 0; i < FM; ++i)
#pragma unroll
    for (int j = 0; j < FN; ++j) acc[i][j] = (f32x4){0.f, 0.f, 0.f, 0.f};

  const unsigned short* agB =
      A + (long)(bm + wave * (TM / 4) + (lane >> 2)) * K +
      ((lane & 3) ^ ((lane >> 3) & 3)) * 8;
  const unsigned short* wgB =
      W + (long)(bn + wave * (TN / 4) + (lane >> 2)) * K +
      ((lane & 3) ^ ((lane >> 3) & 3)) * 8;

  auto STAGE = [&](int k0, int b) {
#pragma unroll
    for (int j = 0; j < IA; ++j)
      gl16(agB + k0 + (long)j * 16 * K, &As[b][(wave * (TM / 4) + j * 16) * 32]);
#pragma unroll
    for (int j = 0; j < IW; ++j)
      gl16(wgB + k0 + (long)j * 16 * K, &Ws[b][(wave * (TN / 4) + j * 16) * 32]);
  };

  auto COMPUTE = [&](int b) {
    bf16x8 af[FM], bg[FN];
    const int sw = ((lane >> 4) ^ ((lane >> 1) & 3)) * 8;
#pragma unroll
    for (int m = 0; m < FM; ++m)
      af[m] = *(const bf16x8*)&As[b][(wr + m * 16 + lr) * 32 + sw];
#pragma unroll
    for (int n = 0; n < FN; ++n)
      bg[n] = *(const bf16x8*)&Ws[b][(wc + n * 16 + lr) * 32 + sw];
    __builtin_amdgcn_s_setprio(1);
#pragma unroll
    for (int m = 0; m < FM; ++m)
#pragma unroll
      for (int n = 0; n < FN; ++n)
        acc[m][n] = __builtin_amdgcn_mfma_f32_16x16x32_bf16(af[m], bg[n],
                                                            acc[m][n], 0, 0, 0);
    __builtin_amdgcn_s_setprio(0);
  };

  const int NT = K >> 5;
  STAGE(0, 0);
  STAGE(32, 1);
  for (int tt = 0; tt < NT; ++tt) {
    if (tt + 2 < NT) {
      STAGE((tt + 2) << 5, (tt + 2) & 3);
      waitv<2 * LPT>();
    } else if (tt + 1 < NT) {
      waitv<LPT>();
    } else {
      waitv<0>();
    }
    __builtin_amdgcn_s_barrier();
    COMPUTE(tt & 3);
    __builtin_amdgcn_sched_barrier(0);
  }

  const int m0 = bm + wr + (lane >> 4) * 4;
  const int n0 = bn + wc + lr;
#pragma unroll
  for (int mi = 0; mi < FM; ++mi)
#pragma unroll
    for (int ni = 0; ni < FN; ++ni) {
      const int n = n0 + ni * 16;
#pragma unroll
      for (int r = 0; r < 4; ++r) {
        const int m = m0 + mi * 16 + r;
        float v = acc[mi][ni][r] + p0[n];
        of[(long)m * N + n] = v;
        ob[(long)m * N + n] = f2b(v);
      }
    }
}

// ---------------------------------------------------------------------------
// mamba5: 5 Mamba blocks fused, grid 256 x 512thr, 32 rows/block, h resident.
// Register-blocked 2x2 (4 MFMA / 4 ds_read per tt) AND deep pipeline:
// tiles [256N x 32K] = 16KB, Ring = 4 x 16KB, depth-3 counted vmcnt
// (waitv<4>/2/0), stage-after-barrier into slot (tt+3)&3 = (tt-1)&3 whose
// reads completed before barrier(tt). Tile swizzle: chunk ^= (row>>1)&3
// (both sides). Fully unrolled -> compile-time offsets. No global loads in
// loops. L=1: conv = tap3*xi+cb (folded); scan -> y = xi*(dt*BC+D)*silu(z).
// SMEM (shorts): XiL[0,16384) SzL[16384,32768) Ring[32768,65536)
//   HLr[65536,73728) Dxl@73728(32x68 f32) BCl@78080 Par@78144(1536 f32)
// ---------------------------------------------------------------------------
__global__ __launch_bounds__(512) void mamba5(
    const unsigned short* __restrict__ hb0, const float* __restrict__ h0,
    const unsigned short* __restrict__ inwb,
    const unsigned short* __restrict__ xwpb,
    const unsigned short* __restrict__ dtwpb,
    const unsigned short* __restrict__ owb,
    const float* __restrict__ conv_b, const float* __restrict__ dt_b,
    const float* __restrict__ Dp, float* __restrict__ hout) {
  __shared__ __align__(16) unsigned short SMEM[81216];
  unsigned short* XiL = SMEM;
  unsigned short* SzL = SMEM + 16384;
  unsigned short* Ring = SMEM + 32768;
  unsigned short* HLr = SMEM + 65536;
  float* Dxl = (float*)(SMEM + 73728);
  float* BCl = (float*)(SMEM + 78080);
  float* Par = (float*)(SMEM + 78144);

  const int t = threadIdx.x, lane = t & 63, w = t >> 6;
  const int lr = lane & 15, lg = lane >> 4;
  const int bm = blockIdx.x * 32;
  const int m04 = lg * 4;             // frag row base within 16-row block
  const int wc32 = w * 32;            // wave's 32-col base
  const int strow = lane >> 2;        // staging row within 16-row group
  const int stc = (lane & 3) ^ ((strow >> 1) & 3);  // pre-swizzled src chunk

  // ---- init: h bf16 -> HLr (chunk-swizzled); fp32 residual -> regs ----
#pragma unroll
  for (int j = 0; j < 2; ++j) {
    const int i = w * 2 + j;
    const int row = 2 * i + (lane >> 5);
    const int c = (lane & 31) ^ (row & 7);
    gl16(hb0 + (long)(bm + row) * 256 + c * 8, HLr + i * 512);
  }
  float hres[2][2][4];
#pragma unroll
  for (int fm = 0; fm < 2; ++fm)
#pragma unroll
    for (int n = 0; n < 2; ++n)
#pragma unroll
      for (int r = 0; r < 4; ++r)
        hres[fm][n][r] =
            h0[(long)(bm + fm * 16 + m04 + r) * 256 + wc32 + n * 16 + lr];
  waitv<0>();
  __builtin_amdgcn_s_barrier();

  for (int blk = 0; blk < 5; ++blk) {
    const unsigned short* inw = inwb + (long)blk * 1024 * 256;
    const unsigned short* xwp = xwpb + (long)blk * 64 * 512;
    const unsigned short* dtwp = dtwpb + (long)blk * 512 * 32;
    const unsigned short* ow = owb + (long)blk * 256 * 512;
    const float* cbv = conv_b + blk * 512;
    const float* dtbv = dt_b + blk * 512;
    const float* Dv = Dp + blk * 512;

    // ===== P1: xz = h @ in_w'^T (conv-folded). 32 tiles [256N x 32K] =====
    auto STAGE1 = [&](int tt, int slot) {
      const int nt = tt >> 3, kq = tt & 7;
#pragma unroll
      for (int j = 0; j < 2; ++j) {
        const int u = w * 2 + j;  // 16 gl16/tile, 16 rows (64B) each
        const int row = u * 16 + strow;
        gl16(inw + (long)(nt * 256 + row) * 256 + kq * 32 + stc * 8,
             Ring + slot * 8192 + u * 512);
      }
    };
    if (w < 6) {  // params -> Par (FIFO-oldest, drained at first waitv)
      const float* ps = (w < 2) ? cbv + (w & 1) * 256
                      : (w < 4) ? dtbv + (w & 1) * 256
                                : Dv + (w & 1) * 256;
      gl16(ps + lane * 4, (unsigned short*)Par + w * 512);
    }
    STAGE1(0, 0); STAGE1(1, 1); STAGE1(2, 2);
    f32x4 acc1[2][2];
#pragma unroll
    for (int tt = 0; tt < 32; ++tt) {
      if (tt + 2 < 32) waitv<4>();
      else if (tt + 1 < 32) waitv<2>();
      else waitv<0>();
      __builtin_amdgcn_s_barrier();
      if (tt + 3 < 32) STAGE1(tt + 3, (tt + 3) & 3);
      __builtin_amdgcn_sched_barrier(0);
      const int nt = tt >> 3, kq = tt & 7;
      if (kq == 0) {
#pragma unroll
        for (int n = 0; n < 2; ++n) {
          const int c = nt * 256 + wc32 + n * 16 + lr;
          const float cb = (nt < 2) ? Par[c] : 0.f;  // conv_b (LDS, no vmcnt)
          acc1[0][n] = (f32x4){cb, cb, cb, cb};
          acc1[1][n] = acc1[0][n];
        }
      }
      const unsigned short* Bs = Ring + (tt & 3) * 8192;
      bf16x8 af[2], bg[2];
#pragma unroll
      for (int fm = 0; fm < 2; ++fm) {
        const int row = fm * 16 + lr;
        af[fm] = *(const bf16x8*)
            &HLr[row * 256 + (((kq * 4 + lg) ^ (row & 7)) * 8)];
      }
#pragma unroll
      for (int n = 0; n < 2; ++n) {
        const int rb = wc32 + n * 16 + lr;  // tile-local row 0..255
        bg[n] = *(const bf16x8*)&Bs[rb * 32 + ((lg ^ ((rb >> 1) & 3)) * 8)];
      }
      __builtin_amdgcn_s_setprio(1);
#pragma unroll
      for (int fm = 0; fm < 2; ++fm)
#pragma unroll
        for (int n = 0; n < 2; ++n)
          acc1[fm][n] = __builtin_amdgcn_mfma_f32_16x16x32_bf16(
              af[fm], bg[n], acc1[fm][n], 0, 0, 0);
      __builtin_amdgcn_s_setprio(0);
      if (kq == 7) {
#pragma unroll
        for (int fm = 0; fm < 2; ++fm)
#pragma unroll
          for (int n = 0; n < 2; ++n) {
            const int c = nt * 256 + wc32 + n * 16 + lr;
#pragma unroll
            for (int r = 0; r < 4; ++r) {
              const int row = fm * 16 + m04 + r;
              const float v = fsilu(acc1[fm][n][r]);
              if (nt < 2)
                XiL[row * 512 + (((c >> 3) ^ (row & 7)) * 8) + (c & 7)] =
                    f2b(v);
              else
                SzL[row * 512 + (c - 512)] = f2b(v);
            }
          }
      }
      __builtin_amdgcn_sched_barrier(0);
    }
    lgkm_bar();  // Xi/Sz visible; Ring reads retired

    // ====== P2: xdbl = xi @ xwp^T (xwp 64KB fills whole Ring) ======
#pragma unroll
    for (int j = 0; j < 8; ++j) {
      const int i = w * 8 + j;  // 64 gl16, 1 row (1KB) each
      gl16(xwp + (long)i * 512 + (lane ^ (i & 7)) * 8, Ring + i * 512);
    }
    waitv<0>();
    __builtin_amdgcn_s_barrier();
    {
      const int fm2 = w & 1, fn2 = w >> 1;
      const int ar = fm2 * 16 + lr, rb = fn2 * 16 + lr;
      f32x4 a2 = {0.f, 0.f, 0.f, 0.f};
      __builtin_amdgcn_s_setprio(1);
#pragma unroll
      for (int kc = 0; kc < 16; ++kc) {
        bf16x8 af = *(const bf16x8*)
            &XiL[ar * 512 + (((kc * 4 + lg) ^ (lr & 7)) * 8)];
        bf16x8 bg = *(const bf16x8*)
            &Ring[rb * 512 + (((kc * 4 + lg) ^ (lr & 7)) * 8)];
        a2 = __builtin_amdgcn_mfma_f32_16x16x32_bf16(af, bg, a2, 0, 0, 0);
      }
      __builtin_amdgcn_s_setprio(0);
#pragma unroll
      for (int r = 0; r < 4; ++r)
        Dxl[(fm2 * 16 + m04 + r) * 68 + fn2 * 16 + lr] = a2[r];
    }
    lgkm_bar();  // Dxl visible; Ring reads retired

    // ===== P4 prologue: dtwp [512x32]=32KB into Ring[0..16384); overlap
    // with BC + afdt prep =====
#pragma unroll
    for (int j = 0; j < 4; ++j) {
      const int u = w * 4 + j;  // 32 gl16, 16 rows (64B) each
      const int row = u * 16 + (lane >> 2);
      const int c = (lane & 3) ^ (row & 3);
      gl16(dtwp + (long)row * 32 + c * 8, Ring + u * 512);
    }
    if (t < 32) {
      float bc = 0.f;
      const float* dx = &Dxl[t * 68];
#pragma unroll
      for (int s2 = 0; s2 < 16; ++s2) bc += dx[16 + s2] * dx[32 + s2];
      BCl[t] = bc;
    }
    bf16x8 afdt;
    {
      // k 16..31 multiply vs zero-padded dtwp rows: contribute 0
      const float* dx = &Dxl[((w & 1) * 16 + lr) * 68 + lg * 8];
#pragma unroll
      for (int e = 0; e < 8; ++e) afdt[e] = (short)f2b(dx[e]);
    }
    waitv<0>();
    lgkm_bar();  // dtwp + BCl visible

    // ===== P4: dt = softplus(xdbl[:,:16]@dtwp^T + dtb); y (barrier-free) ==
    {
      const int fn4 = w >> 1, m04b = (w & 1) * 16 + m04;
#pragma unroll
      for (int tt = 0; tt < 8; ++tt) {
        const int d = tt * 64 + fn4 * 16 + lr;
        bf16x8 bg = *(const bf16x8*)&Ring[d * 32 + ((lg ^ (d & 3)) * 8)];
        f32x4 da = __builtin_amdgcn_mfma_f32_16x16x32_bf16(
            afdt, bg, (f32x4){0.f, 0.f, 0.f, 0.f}, 0, 0, 0);
        const float dbv = Par[512 + d], dvv = Par[1024 + d];
#pragma unroll
        for (int r = 0; r < 4; ++r) {
          const int row = m04b + r;
          const float dtv = fsoftplus(da[r] + dbv);
          const int xoff = row * 512 + (((d >> 3) ^ (row & 7)) * 8) + (d & 7);
          const float y = b2f(XiL[xoff]) * (dtv * BCl[row] + dvv) *
                          b2f(SzL[row * 512 + d]);
          XiL[xoff] = f2b(y);  // y overwrites xi in place
        }
      }
    }
    lgkm_bar();  // y visible; dtwp reads retired

    // ===== P5: h += y @ ow^T. 16 tiles [256N x 32K], ring-4 depth-3 =====
    auto STAGE5 = [&](int tt, int slot) {
#pragma unroll
      for (int j = 0; j < 2; ++j) {
        const int u = w * 2 + j;
        const int row = u * 16 + strow;
        gl16(ow + (long)row * 512 + tt * 32 + stc * 8,
             Ring + slot * 8192 + u * 512);
      }
    };
    STAGE5(0, 0); STAGE5(1, 1); STAGE5(2, 2);
    f32x4 acc5[2][2];
#pragma unroll
    for (int fm = 0; fm < 2; ++fm)
#pragma unroll
      for (int n = 0; n < 2; ++n) acc5[fm][n] = (f32x4){0.f, 0.f, 0.f, 0.f};
#pragma unroll
    for (int tt = 0; tt < 16; ++tt) {
      if (tt + 2 < 16) waitv<4>();
      else if (tt + 1 < 16) waitv<2>();
      else waitv<0>();
      __builtin_amdgcn_s_barrier();
      if (tt + 3 < 16) STAGE5(tt + 3, (tt + 3) & 3);
      __builtin_amdgcn_sched_barrier(0);
      const unsigned short* Bs = Ring + (tt & 3) * 8192;
      bf16x8 af[2], bg[2];
#pragma unroll
      for (int fm = 0; fm < 2; ++fm) {
        const int row = fm * 16 + lr;
        af[fm] = *(const bf16x8*)
            &XiL[row * 512 + (((tt * 4 + lg) ^ (row & 7)) * 8)];
      }
#pragma unroll
      for (int n = 0; n < 2; ++n) {
        const int rb = wc32 + n * 16 + lr;
        bg[n] = *(const bf16x8*)&Bs[rb * 32 + ((lg ^ ((rb >> 1) & 3)) * 8)];
      }
      __builtin_amdgcn_s_setprio(1);
#pragma unroll
      for (int fm = 0; fm < 2; ++fm)
#pragma unroll
        for (int n = 0; n < 2; ++n)
          acc5[fm][n] = __builtin_amdgcn_mfma_f32_16x16x32_bf16(
              af[fm], bg[n], acc5[fm][n], 0, 0, 0);
      __builtin_amdgcn_s_setprio(0);
      __builtin_amdgcn_sched_barrier(0);
    }
    // epilogue: h += acc; bf16 h -> HLr (swizzled) for next block's P1
#pragma unroll
    for (int fm = 0; fm < 2; ++fm)
#pragma unroll
      for (int n = 0; n < 2; ++n) {
        const int col = wc32 + n * 16 + lr;
#pragma unroll
        for (int r = 0; r < 4; ++r) {
          const int row = fm * 16 + m04 + r;
          const float v = acc5[fm][n][r] + hres[fm][n][r];
          hres[fm][n][r] = v;
          HLr[row * 256 + (((col >> 3) ^ (row & 7)) * 8) + (col & 7)] = f2b(v);
        }
      }
    lgkm_bar();  // new h visible for next blk's P1
  }

  // ---- final h fp32 write for LN+cls ----
#pragma unroll
  for (int fm = 0; fm < 2; ++fm)
#pragma unroll
    for (int n = 0; n < 2; ++n)
#pragma unroll
      for (int r = 0; r < 4; ++r)
        hout[(long)(bm + fm * 16 + m04 + r) * 256 + wc32 + n * 16 + lr] =
            hres[fm][n][r];
}

// x fp32 -> bf16 streaming cast
__global__ __launch_bounds__(256) void castx(const float* __restrict__ s,
                                             unsigned short* __restrict__ d) {
  const int n4 = (8192 * 2048) / 4;
  for (int i = blockIdx.x * 256 + threadIdx.x; i < n4; i += gridDim.x * 256) {
    float4v v = ((const float4v*)s)[i];
    s16x4 o;
    o[0] = (short)f2b(v[0]); o[1] = (short)f2b(v[1]);
    o[2] = (short)f2b(v[2]); o[3] = (short)f2b(v[3]);
    ((s16x4*)d)[i] = o;
  }
}

// weight precast: W_pre -> bf16; in_w -> bf16 with conv tap3 folded into
// rows <512; out_w -> bf16; x_proj -> padded [64x512]; dt_w -> padded [512x32]
__global__ __launch_bounds__(256) void precast(
    const float* __restrict__ wpre, const float* __restrict__ inw,
    const float* __restrict__ ow, const float* __restrict__ xw,
    const float* __restrict__ dtw, const float* __restrict__ cw,
    unsigned short* __restrict__ wpreb, unsigned short* __restrict__ inwb,
    unsigned short* __restrict__ owb, unsigned short* __restrict__ xwpb,
    unsigned short* __restrict__ dtwpb) {
  const int S0 = 524288;         // 256*2048
  const int S1 = S0 + 1310720;   // + 5*1024*256
  const int S2 = S1 + 655360;    // + 5*256*512
  const int S3 = S2 + 163840;    // + 5*64*512
  const int S4 = S3 + 81920;     // + 5*512*32
  int i4 = (blockIdx.x * 256 + threadIdx.x) * 4;
  if (i4 >= S4) return;
  float4v v = {0.f, 0.f, 0.f, 0.f};
  unsigned short* dst;
  if (i4 < S0) {
    v = *(const float4v*)(wpre + i4);
    dst = wpreb + i4;
  } else if (i4 < S1) {
    int o = i4 - S0;
    v = *(const float4v*)(inw + o);
    int b = o >> 18, row = (o >> 8) & 1023;
    if (row < 512) {
      float c3 = cw[(b * 512 + row) * 4 + 3];
      v[0] *= c3; v[1] *= c3; v[2] *= c3; v[3] *= c3;
    }
    dst = inwb + o;
  } else if (i4 < S2) {
    int o = i4 - S1;
    v = *(const float4v*)(ow + o);
    dst = owb + o;
  } else if (i4 < S3) {
    int o = i4 - S2;
    dst = xwpb + o;
    int k = o & 511, j = (o >> 9) & 63, b = o >> 15;
    if (j < 48) v = *(const float4v*)(xw + ((long)(b * 48 + j)) * 512 + k);
  } else {
    int o = i4 - S3;
    dst = dtwpb + o;
    int k = o & 31, dd = o >> 5;
    if (k < 16) v = *(const float4v*)(dtw + (long)dd * 16 + k);
  }
  s16x4 sv;
  sv[0] = (short)f2b(v[0]); sv[1] = (short)f2b(v[1]);
  sv[2] = (short)f2b(v[2]); sv[3] = (short)f2b(v[3]);
  *(s16x4*)dst = sv;
}

// LayerNorm(256) + classifier (8 outputs). One wave per row.
__global__ __launch_bounds__(256) void final_ln_cls(
    const float* __restrict__ h, const float* __restrict__ g,
    const float* __restrict__ be, const float* __restrict__ Wc,
    const float* __restrict__ bc, float* __restrict__ out) {
  const int wave = threadIdx.x >> 6, lane = threadIdx.x & 63;
  const int row = blockIdx.x * 4 + wave;
  const float4v* hr = (const float4v*)(h + (long)row * 256);
  float4v v = hr[lane];
  float s = v[0] + v[1] + v[2] + v[3];
#pragma unroll
  for (int o = 32; o; o >>= 1) s += __shfl_xor(s, o);
  const float mu = s * (1.f / 256.f);
  float d0 = v[0] - mu, d1 = v[1] - mu, d2 = v[2] - mu, d3 = v[3] - mu;
  float qq = d0 * d0 + d1 * d1 + d2 * d2 + d3 * d3;
#pragma unroll
  for (int o = 32; o; o >>= 1) qq += __shfl_xor(qq, o);
  const float rs = rsqrtf(qq * (1.f / 256.f) + 1e-5f);
  const float4v gv = ((const float4v*)g)[lane];
  const float4v bv = ((const float4v*)be)[lane];
  float hn[4];
  hn[0] = d0 * rs * gv[0] + bv[0];
  hn[1] = d1 * rs * gv[1] + bv[1];
  hn[2] = d2 * rs * gv[2] + bv[2];
  hn[3] = d3 * rs * gv[3] + bv[3];
  float lg[8];
#pragma unroll
  for (int o = 0; o < 8; ++o) {
    const float4v wv = ((const float4v*)(Wc + o * 256))[lane];
    float p = hn[0] * wv[0] + hn[1] * wv[1] + hn[2] * wv[2] + hn[3] * wv[3];
#pragma unroll
    for (int x = 32; x; x >>= 1) p += __shfl_xor(p, x);
    lg[o] = p;
  }
  if (lane == 0) {
#pragma unroll
    for (int o = 0; o < 8; ++o) out[(long)row * 8 + o] = lg[o] + bc[o];
  }
}

extern "C" void kernel_launch(void* const* d_in, const int* in_sizes, int n_in,
                              void* d_out, int out_size, void* d_ws,
                              size_t ws_size, hipStream_t stream) {
  const float* x      = (const float*)d_in[0];
  const float* W_pre  = (const float*)d_in[1];
  const float* b_pre  = (const float*)d_in[2];
  const float* in_w   = (const float*)d_in[3];
  const float* conv_w = (const float*)d_in[4];
  const float* conv_b = (const float*)d_in[5];
  const float* x_w    = (const float*)d_in[6];
  const float* dt_w   = (const float*)d_in[7];
  const float* dt_b   = (const float*)d_in[8];
  // d_in[9] = A_log: dead (scan starts from h0=0 and L=1)
  const float* Dp     = (const float*)d_in[10];
  const float* out_w  = (const float*)d_in[11];
  const float* ln_g   = (const float*)d_in[12];
  const float* ln_b   = (const float*)d_in[13];
  const float* W_cls  = (const float*)d_in[14];
  const float* b_cls  = (const float*)d_in[15];
  float* out = (float*)d_out;

  char* w = (char*)d_ws;
  unsigned short* wpreb = (unsigned short*)w; w += 256 * 2048 * 2;
  unsigned short* inwb  = (unsigned short*)w; w += 5 * 1024 * 256 * 2;
  unsigned short* xwpb  = (unsigned short*)w; w += 5 * 64 * 512 * 2;
  unsigned short* owb   = (unsigned short*)w; w += 5 * 256 * 512 * 2;
  unsigned short* dtwpb = (unsigned short*)w; w += 5 * 512 * 32 * 2;
  float*          h     = (float*)w;          w += 8192 * 256 * 4;
  unsigned short* hb    = (unsigned short*)w; w += 8192 * 256 * 2;
  unsigned short* xb    = (unsigned short*)w; w += 8192 * 2048 * 2;

  precast<<<2672, 256, 0, stream>>>(W_pre, in_w, out_w, x_w, dt_w, conv_w,
                                    wpreb, inwb, owb, xwpb, dtwpb);
  castx<<<2048, 256, 0, stream>>>(x, xb);

  // h = x @ W_pre^T + b_pre  (fp32 of + bf16 ob)
  gemm_pl<128, 64><<<256, 256, 0, stream>>>(
      xb, wpreb, 256, 2048, 4, b_pre, h, hb);

  // all 5 Mamba blocks, one persistent kernel, h resident
  mamba5<<<256, 512, 0, stream>>>(hb, h, inwb, xwpb, dtwpb, owb,
                                  conv_b, dt_b, Dp, h);

  final_ln_cls<<<2048, 256, 0, stream>>>(h, ln_g, ln_b, W_cls, b_cls, out);
}

// Round 13
// 189.693 us; speedup vs baseline: 1.2834x; 1.1396x over previous
//
#include <hip/hip_runtime.h>
#include <hip/hip_bf16.h>

typedef __attribute__((ext_vector_type(8))) short bf16x8;
typedef __attribute__((ext_vector_type(4))) short s16x4;
typedef __attribute__((ext_vector_type(4))) float f32x4;
typedef __attribute__((ext_vector_type(4))) float float4v;

static __device__ __forceinline__ unsigned short f2b(float f) {
  unsigned int u = __builtin_bit_cast(unsigned int, f);
  u += 0x7fffu + ((u >> 16) & 1u);
  return (unsigned short)(u >> 16);
}
static __device__ __forceinline__ float b2f(unsigned short s) {
  unsigned int u = ((unsigned int)s) << 16;
  return __builtin_bit_cast(float, u);
}
// fast silu/softplus on TRANS pipe; bf16-accurate
static __device__ __forceinline__ float fsilu(float x) {
  float e = __builtin_amdgcn_exp2f(-1.44269504f * x);
  return x * __builtin_amdgcn_rcpf(1.f + e);
}
static __device__ __forceinline__ float fsoftplus(float a) {
  if (a > 20.f) return a;
  float t = __builtin_amdgcn_exp2f(1.44269504f * a);
  return 0.69314718f * __builtin_amdgcn_logf(1.f + t);
}
// async global->LDS, 16B/lane; dest wave-uniform base + lane*16,
// source per-lane (enables source-side swizzling, rule #21)
static __device__ __forceinline__ void gl16(const void* g, void* l) {
  __builtin_amdgcn_global_load_lds(
      (const __attribute__((address_space(1))) unsigned int*)g,
      (__attribute__((address_space(3))) unsigned int*)l, 16, 0, 0);
}
template <int N>
static __device__ __forceinline__ void waitv() {
  if constexpr (N == 0) asm volatile("s_waitcnt vmcnt(0)" ::: "memory");
  else if constexpr (N == 1) asm volatile("s_waitcnt vmcnt(1)" ::: "memory");
  else if constexpr (N == 2) asm volatile("s_waitcnt vmcnt(2)" ::: "memory");
  else if constexpr (N == 3) asm volatile("s_waitcnt vmcnt(3)" ::: "memory");
  else if constexpr (N == 4) asm volatile("s_waitcnt vmcnt(4)" ::: "memory");
  else if constexpr (N == 5) asm volatile("s_waitcnt vmcnt(5)" ::: "memory");
  else if constexpr (N == 6) asm volatile("s_waitcnt vmcnt(6)" ::: "memory");
  else if constexpr (N == 8) asm volatile("s_waitcnt vmcnt(8)" ::: "memory");
}
static __device__ __forceinline__ void lgkm_bar() {
  asm volatile("s_waitcnt lgkmcnt(0)" ::: "memory");
  __builtin_amdgcn_s_barrier();
}

// ---------------------------------------------------------------------------
// pre-GEMM: C = A @ W^T + bias, bf16 MFMA, fp32 accum. 128x64, BK=32,
// 4 waves, depth-4 ring, counted vmcnt, chunk-XOR swizzle, XCD swizzle.
// ---------------------------------------------------------------------------
template <int TM, int TN>
__global__ __launch_bounds__(256) void gemm_pl(
    const unsigned short* __restrict__ A, const unsigned short* __restrict__ W,
    int N, int K, int GY,
    const float* __restrict__ p0, float* __restrict__ of,
    unsigned short* __restrict__ ob) {
  constexpr int FM = TM / 32, FN = TN / 32;
  constexpr int IA = TM / 64, IW = TN / 64;
  constexpr int LPT = IA + IW;
  __shared__ __align__(16) unsigned short As[4][TM * 32];
  __shared__ __align__(16) unsigned short Ws[4][TN * 32];

  const int t = threadIdx.x, lane = t & 63, wave = t >> 6;
  const int lr = lane & 15;
  const int q = gridDim.x >> 3;
  const int s = (blockIdx.x & 7) * q + (blockIdx.x >> 3);
  const int bm = (s / GY) * TM, bn = (s % GY) * TN;
  const int wr = (wave >> 1) * (TM / 2), wc = (wave & 1) * (TN / 2);

  f32x4 acc[FM][FN];
#pragma unroll
  for (int i = 0; i < FM; ++i)
#pragma unroll
    for (int j = 0; j < FN; ++j) acc[i][j] = (f32x4){0.f, 0.f, 0.f, 0.f};

  const unsigned short* agB =
      A + (long)(bm + wave * (TM / 4) + (lane >> 2)) * K +
      ((lane & 3) ^ ((lane >> 3) & 3)) * 8;
  const unsigned short* wgB =
      W + (long)(bn + wave * (TN / 4) + (lane >> 2)) * K +
      ((lane & 3) ^ ((lane >> 3) & 3)) * 8;

  auto STAGE = [&](int k0, int b) {
#pragma unroll
    for (int j = 0; j < IA; ++j)
      gl16(agB + k0 + (long)j * 16 * K, &As[b][(wave * (TM / 4) + j * 16) * 32]);
#pragma unroll
    for (int j = 0; j < IW; ++j)
      gl16(wgB + k0 + (long)j * 16 * K, &Ws[b][(wave * (TN / 4) + j * 16) * 32]);
  };

  auto COMPUTE = [&](int b) {
    bf16x8 af[FM], bg[FN];
    const int sw = ((lane >> 4) ^ ((lane >> 1) & 3)) * 8;
#pragma unroll
    for (int m = 0; m < FM; ++m)
      af[m] = *(const bf16x8*)&As[b][(wr + m * 16 + lr) * 32 + sw];
#pragma unroll
    for (int n = 0; n < FN; ++n)
      bg[n] = *(const bf16x8*)&Ws[b][(wc + n * 16 + lr) * 32 + sw];
    __builtin_amdgcn_s_setprio(1);
#pragma unroll
    for (int m = 0; m < FM; ++m)
#pragma unroll
      for (int n = 0; n < FN; ++n)
        acc[m][n] = __builtin_amdgcn_mfma_f32_16x16x32_bf16(af[m], bg[n],
                                                            acc[m][n], 0, 0, 0);
    __builtin_amdgcn_s_setprio(0);
  };

  const int NT = K >> 5;
  STAGE(0, 0);
  STAGE(32, 1);
  for (int tt = 0; tt < NT; ++tt) {
    if (tt + 2 < NT) {
      STAGE((tt + 2) << 5, (tt + 2) & 3);
      waitv<2 * LPT>();
    } else if (tt + 1 < NT) {
      waitv<LPT>();
    } else {
      waitv<0>();
    }
    __builtin_amdgcn_s_barrier();
    COMPUTE(tt & 3);
    __builtin_amdgcn_sched_barrier(0);
  }

  const int m0 = bm + wr + (lane >> 4) * 4;
  const int n0 = bn + wc + lr;
#pragma unroll
  for (int mi = 0; mi < FM; ++mi)
#pragma unroll
    for (int ni = 0; ni < FN; ++ni) {
      const int n = n0 + ni * 16;
#pragma unroll
      for (int r = 0; r < 4; ++r) {
        const int m = m0 + mi * 16 + r;
        float v = acc[mi][ni][r] + p0[n];
        of[(long)m * N + n] = v;
        ob[(long)m * N + n] = f2b(v);
      }
    }
}

// ---------------------------------------------------------------------------
// mamba5: 5 Mamba blocks fused, grid 256 x 512thr, 32 rows/block, h resident.
// DEPTH-7 pipeline: tiles [128N x 32K] = 8KB, Ring = 8 x 8KB, 1 gl16 per
// wave per tile, stage tt+7 after barrier(tt), uniform vmcnt(6) mid-loop
// (7KB outstanding/wave = 56KB/CU, covers ~900cyc HBM-miss latency).
// Wave layout: 2 row-groups x 4 col-groups; wave = 16 rows x 32 cols,
// 2 MFMA + 3 ds_read per tt. Slot (tt+7)&7 = (tt-1)&7, reads retired
// pre-barrier. Tile swizzle chunk ^= (row>>1)&3 both-sides. No global
// loads in loops (conv tap3 folded into inwb; cb/dtb/D in Par LDS).
// L=1: conv = tap3*xi+cb; scan -> y = xi*(dt*BC+D)*silu(z).
// SMEM (shorts): XiL[0,16384) SzL[16384,32768) Ring[32768,65536)
//   HLr[65536,73728) Dxl@73728(32x68 f32) BCl@78080 Par@78144(1536 f32)
// ---------------------------------------------------------------------------
__global__ __launch_bounds__(512) void mamba5(
    const unsigned short* __restrict__ hb0, const float* __restrict__ h0,
    const unsigned short* __restrict__ inwb,
    const unsigned short* __restrict__ xwpb,
    const unsigned short* __restrict__ dtwpb,
    const unsigned short* __restrict__ owb,
    const float* __restrict__ conv_b, const float* __restrict__ dt_b,
    const float* __restrict__ Dp, float* __restrict__ hout) {
  __shared__ __align__(16) unsigned short SMEM[81216];
  unsigned short* XiL = SMEM;
  unsigned short* SzL = SMEM + 16384;
  unsigned short* Ring = SMEM + 32768;
  unsigned short* HLr = SMEM + 65536;
  float* Dxl = (float*)(SMEM + 73728);
  float* BCl = (float*)(SMEM + 78080);
  float* Par = (float*)(SMEM + 78144);

  const int t = threadIdx.x, lane = t & 63, w = t >> 6;
  const int lr = lane & 15, lg = lane >> 4;
  const int bm = blockIdx.x * 32;
  const int m04 = lg * 4;             // frag row base within 16-row block
  const int rg16 = (w >> 2) * 16;     // wave's row group: 0 / 16
  const int cg32 = (w & 3) * 32;      // wave's col group within 128-col tile
  const int strow = lane >> 2;        // staging row within 16-row group
  const int stc = (lane & 3) ^ ((strow >> 1) & 3);  // pre-swizzled src chunk

  // ---- init: h bf16 -> HLr (chunk-swizzled); fp32 residual -> regs ----
#pragma unroll
  for (int j = 0; j < 2; ++j) {
    const int i = w * 2 + j;
    const int row = 2 * i + (lane >> 5);
    const int c = (lane & 31) ^ (row & 7);
    gl16(hb0 + (long)(bm + row) * 256 + c * 8, HLr + i * 512);
  }
  float hres[2][2][4];
#pragma unroll
  for (int ng = 0; ng < 2; ++ng)
#pragma unroll
    for (int n = 0; n < 2; ++n)
#pragma unroll
      for (int r = 0; r < 4; ++r)
        hres[ng][n][r] = h0[(long)(bm + rg16 + m04 + r) * 256 + ng * 128 +
                            cg32 + n * 16 + lr];
  waitv<0>();
  __builtin_amdgcn_s_barrier();

  for (int blk = 0; blk < 5; ++blk) {
    const unsigned short* inw = inwb + (long)blk * 1024 * 256;
    const unsigned short* xwp = xwpb + (long)blk * 64 * 512;
    const unsigned short* dtwp = dtwpb + (long)blk * 512 * 32;
    const unsigned short* ow = owb + (long)blk * 256 * 512;
    const float* cbv = conv_b + blk * 512;
    const float* dtbv = dt_b + blk * 512;
    const float* Dv = Dp + blk * 512;

    // ===== P1: xz = h @ in_w'^T. 64 tiles [128N x 32K], depth-7 =====
    auto STAGE1 = [&](int tt, int slot) {
      const int nt = tt >> 3, kq = tt & 7;
      gl16(inw + (long)(nt * 128 + w * 16 + strow) * 256 + kq * 32 + stc * 8,
           Ring + slot * 4096 + w * 512);
    };
    if (w < 6) {  // params -> Par (oldest in FIFO, drained at first waitv)
      const float* ps = (w < 2) ? cbv + (w & 1) * 256
                      : (w < 4) ? dtbv + (w & 1) * 256
                                : Dv + (w & 1) * 256;
      gl16(ps + lane * 4, (unsigned short*)Par + w * 512);
    }
    STAGE1(0, 0); STAGE1(1, 1); STAGE1(2, 2); STAGE1(3, 3);
    STAGE1(4, 4); STAGE1(5, 5); STAGE1(6, 6);
    f32x4 acc1[2];
#pragma unroll
    for (int tt = 0; tt < 64; ++tt) {
      if (tt <= 57) waitv<6>();
      else if (tt == 58) waitv<5>();
      else if (tt == 59) waitv<4>();
      else if (tt == 60) waitv<3>();
      else if (tt == 61) waitv<2>();
      else if (tt == 62) waitv<1>();
      else waitv<0>();
      __builtin_amdgcn_s_barrier();
      if (tt + 7 < 64) STAGE1(tt + 7, (tt + 7) & 7);
      __builtin_amdgcn_sched_barrier(0);
      const int nt = tt >> 3, kq = tt & 7;
      if (kq == 0) {
#pragma unroll
        for (int n = 0; n < 2; ++n) {
          const int c = nt * 128 + cg32 + n * 16 + lr;
          const float cb = (nt < 4) ? Par[c] : 0.f;  // LDS (no vmcnt)
          acc1[n] = (f32x4){cb, cb, cb, cb};
        }
      }
      const unsigned short* Bs = Ring + (tt & 7) * 4096;
      const int ar = rg16 + lr;
      bf16x8 af = *(const bf16x8*)
          &HLr[ar * 256 + (((kq * 4 + lg) ^ (ar & 7)) * 8)];
      bf16x8 bg[2];
#pragma unroll
      for (int n = 0; n < 2; ++n) {
        const int rb = cg32 + n * 16 + lr;  // tile-local row 0..127
        bg[n] = *(const bf16x8*)&Bs[rb * 32 + ((lg ^ ((rb >> 1) & 3)) * 8)];
      }
      __builtin_amdgcn_s_setprio(1);
#pragma unroll
      for (int n = 0; n < 2; ++n)
        acc1[n] = __builtin_amdgcn_mfma_f32_16x16x32_bf16(af, bg[n], acc1[n],
                                                          0, 0, 0);
      __builtin_amdgcn_s_setprio(0);
      if (kq == 7) {
#pragma unroll
        for (int n = 0; n < 2; ++n) {
          const int c = nt * 128 + cg32 + n * 16 + lr;
#pragma unroll
          for (int r = 0; r < 4; ++r) {
            const int row = rg16 + m04 + r;
            const float v = fsilu(acc1[n][r]);
            if (nt < 4)
              XiL[row * 512 + (((c >> 3) ^ (row & 7)) * 8) + (c & 7)] = f2b(v);
            else
              SzL[row * 512 + (c - 512)] = f2b(v);
          }
        }
      }
      __builtin_amdgcn_sched_barrier(0);
    }
    lgkm_bar();  // Xi/Sz visible; Ring reads retired

    // ====== P2: xdbl = xi @ xwp^T (xwp 64KB fills whole Ring) ======
#pragma unroll
    for (int j = 0; j < 8; ++j) {
      const int i = w * 8 + j;  // 64 gl16, 1 row (1KB) each
      gl16(xwp + (long)i * 512 + (lane ^ (i & 7)) * 8, Ring + i * 512);
    }
    waitv<0>();
    __builtin_amdgcn_s_barrier();
    {
      const int fm2 = w & 1, fn2 = w >> 1;
      const int ar = fm2 * 16 + lr, rb = fn2 * 16 + lr;
      f32x4 a2 = {0.f, 0.f, 0.f, 0.f};
      __builtin_amdgcn_s_setprio(1);
#pragma unroll
      for (int kc = 0; kc < 16; ++kc) {
        bf16x8 af = *(const bf16x8*)
            &XiL[ar * 512 + (((kc * 4 + lg) ^ (lr & 7)) * 8)];
        bf16x8 bg = *(const bf16x8*)
            &Ring[rb * 512 + (((kc * 4 + lg) ^ (lr & 7)) * 8)];
        a2 = __builtin_amdgcn_mfma_f32_16x16x32_bf16(af, bg, a2, 0, 0, 0);
      }
      __builtin_amdgcn_s_setprio(0);
#pragma unroll
      for (int r = 0; r < 4; ++r)
        Dxl[(fm2 * 16 + m04 + r) * 68 + fn2 * 16 + lr] = a2[r];
    }
    lgkm_bar();  // Dxl visible; Ring reads retired

    // ===== P4 prologue: dtwp [512x32]=32KB into Ring[0..16384); overlap
    // with BC + afdt prep =====
#pragma unroll
    for (int j = 0; j < 4; ++j) {
      const int u = w * 4 + j;  // 32 gl16, 16 rows (64B) each
      const int row = u * 16 + (lane >> 2);
      const int c = (lane & 3) ^ (row & 3);
      gl16(dtwp + (long)row * 32 + c * 8, Ring + u * 512);
    }
    if (t < 32) {
      float bc = 0.f;
      const float* dx = &Dxl[t * 68];
#pragma unroll
      for (int s2 = 0; s2 < 16; ++s2) bc += dx[16 + s2] * dx[32 + s2];
      BCl[t] = bc;
    }
    bf16x8 afdt;
    {
      // k 16..31 multiply vs zero-padded dtwp rows: contribute 0
      const float* dx = &Dxl[((w & 1) * 16 + lr) * 68 + lg * 8];
#pragma unroll
      for (int e = 0; e < 8; ++e) afdt[e] = (short)f2b(dx[e]);
    }
    waitv<0>();
    lgkm_bar();  // dtwp + BCl visible

    // ===== P4: dt = softplus(xdbl[:,:16]@dtwp^T + dtb); y (barrier-free) ==
    {
      const int fn4 = w >> 1, m04b = (w & 1) * 16 + m04;
#pragma unroll
      for (int tt = 0; tt < 8; ++tt) {
        const int d = tt * 64 + fn4 * 16 + lr;
        bf16x8 bg = *(const bf16x8*)&Ring[d * 32 + ((lg ^ (d & 3)) * 8)];
        f32x4 da = __builtin_amdgcn_mfma_f32_16x16x32_bf16(
            afdt, bg, (f32x4){0.f, 0.f, 0.f, 0.f}, 0, 0, 0);
        const float dbv = Par[512 + d], dvv = Par[1024 + d];
#pragma unroll
        for (int r = 0; r < 4; ++r) {
          const int row = m04b + r;
          const float dtv = fsoftplus(da[r] + dbv);
          const int xoff = row * 512 + (((d >> 3) ^ (row & 7)) * 8) + (d & 7);
          const float y = b2f(XiL[xoff]) * (dtv * BCl[row] + dvv) *
                          b2f(SzL[row * 512 + d]);
          XiL[xoff] = f2b(y);  // y overwrites xi in place
        }
      }
    }
    lgkm_bar();  // y visible; dtwp reads retired

    // ===== P5: h += y @ ow^T. 32 tiles [128N x 32K], depth-7 =====
    auto STAGE5 = [&](int tt, int slot) {
      const int ng = tt >> 4, kq = tt & 15;
      gl16(ow + (long)(ng * 128 + w * 16 + strow) * 512 + kq * 32 + stc * 8,
           Ring + slot * 4096 + w * 512);
    };
    STAGE5(0, 0); STAGE5(1, 1); STAGE5(2, 2); STAGE5(3, 3);
    STAGE5(4, 4); STAGE5(5, 5); STAGE5(6, 6);
    f32x4 acc5[2];
#pragma unroll
    for (int tt = 0; tt < 32; ++tt) {
      if (tt <= 25) waitv<6>();
      else if (tt == 26) waitv<5>();
      else if (tt == 27) waitv<4>();
      else if (tt == 28) waitv<3>();
      else if (tt == 29) waitv<2>();
      else if (tt == 30) waitv<1>();
      else waitv<0>();
      __builtin_amdgcn_s_barrier();
      if (tt + 7 < 32) STAGE5(tt + 7, (tt + 7) & 7);
      __builtin_amdgcn_sched_barrier(0);
      const int ng = tt >> 4, kq = tt & 15;
      if (kq == 0) {
        acc5[0] = (f32x4){0.f, 0.f, 0.f, 0.f};
        acc5[1] = (f32x4){0.f, 0.f, 0.f, 0.f};
      }
      const unsigned short* Bs = Ring + (tt & 7) * 4096;
      const int ar = rg16 + lr;
      bf16x8 af = *(const bf16x8*)
          &XiL[ar * 512 + (((kq * 4 + lg) ^ (ar & 7)) * 8)];
      bf16x8 bg[2];
#pragma unroll
      for (int n = 0; n < 2; ++n) {
        const int rb = cg32 + n * 16 + lr;
        bg[n] = *(const bf16x8*)&Bs[rb * 32 + ((lg ^ ((rb >> 1) & 3)) * 8)];
      }
      __builtin_amdgcn_s_setprio(1);
#pragma unroll
      for (int n = 0; n < 2; ++n)
        acc5[n] = __builtin_amdgcn_mfma_f32_16x16x32_bf16(af, bg[n], acc5[n],
                                                          0, 0, 0);
      __builtin_amdgcn_s_setprio(0);
      if (kq == 15) {
#pragma unroll
        for (int n = 0; n < 2; ++n) {
          const int col = ng * 128 + cg32 + n * 16 + lr;
#pragma unroll
          for (int r = 0; r < 4; ++r) {
            const int row = rg16 + m04 + r;
            const float v = acc5[n][r] + hres[ng][n][r];
            hres[ng][n][r] = v;
            HLr[row * 256 + (((col >> 3) ^ (row & 7)) * 8) + (col & 7)] =
                f2b(v);
          }
        }
      }
      __builtin_amdgcn_sched_barrier(0);
    }
    lgkm_bar();  // new h visible for next blk's P1
  }

  // ---- final h fp32 write for LN+cls ----
#pragma unroll
  for (int ng = 0; ng < 2; ++ng)
#pragma unroll
    for (int n = 0; n < 2; ++n)
#pragma unroll
      for (int r = 0; r < 4; ++r)
        hout[(long)(bm + rg16 + m04 + r) * 256 + ng * 128 + cg32 + n * 16 +
             lr] = hres[ng][n][r];
}

// x fp32 -> bf16 streaming cast
__global__ __launch_bounds__(256) void castx(const float* __restrict__ s,
                                             unsigned short* __restrict__ d) {
  const int n4 = (8192 * 2048) / 4;
  for (int i = blockIdx.x * 256 + threadIdx.x; i < n4; i += gridDim.x * 256) {
    float4v v = ((const float4v*)s)[i];
    s16x4 o;
    o[0] = (short)f2b(v[0]); o[1] = (short)f2b(v[1]);
    o[2] = (short)f2b(v[2]); o[3] = (short)f2b(v[3]);
    ((s16x4*)d)[i] = o;
  }
}

// weight precast: W_pre -> bf16; in_w -> bf16 with conv tap3 folded into
// rows <512; out_w -> bf16; x_proj -> padded [64x512]; dt_w -> padded [512x32]
__global__ __launch_bounds__(256) void precast(
    const float* __restrict__ wpre, const float* __restrict__ inw,
    const float* __restrict__ ow, const float* __restrict__ xw,
    const float* __restrict__ dtw, const float* __restrict__ cw,
    unsigned short* __restrict__ wpreb, unsigned short* __restrict__ inwb,
    unsigned short* __restrict__ owb, unsigned short* __restrict__ xwpb,
    unsigned short* __restrict__ dtwpb) {
  const int S0 = 524288;         // 256*2048
  const int S1 = S0 + 1310720;   // + 5*1024*256
  const int S2 = S1 + 655360;    // + 5*256*512
  const int S3 = S2 + 163840;    // + 5*64*512
  const int S4 = S3 + 81920;     // + 5*512*32
  int i4 = (blockIdx.x * 256 + threadIdx.x) * 4;
  if (i4 >= S4) return;
  float4v v = {0.f, 0.f, 0.f, 0.f};
  unsigned short* dst;
  if (i4 < S0) {
    v = *(const float4v*)(wpre + i4);
    dst = wpreb + i4;
  } else if (i4 < S1) {
    int o = i4 - S0;
    v = *(const float4v*)(inw + o);
    int b = o >> 18, row = (o >> 8) & 1023;
    if (row < 512) {
      float c3 = cw[(b * 512 + row) * 4 + 3];
      v[0] *= c3; v[1] *= c3; v[2] *= c3; v[3] *= c3;
    }
    dst = inwb + o;
  } else if (i4 < S2) {
    int o = i4 - S1;
    v = *(const float4v*)(ow + o);
    dst = owb + o;
  } else if (i4 < S3) {
    int o = i4 - S2;
    dst = xwpb + o;
    int k = o & 511, j = (o >> 9) & 63, b = o >> 15;
    if (j < 48) v = *(const float4v*)(xw + ((long)(b * 48 + j)) * 512 + k);
  } else {
    int o = i4 - S3;
    dst = dtwpb + o;
    int k = o & 31, dd = o >> 5;
    if (k < 16) v = *(const float4v*)(dtw + (long)dd * 16 + k);
  }
  s16x4 sv;
  sv[0] = (short)f2b(v[0]); sv[1] = (short)f2b(v[1]);
  sv[2] = (short)f2b(v[2]); sv[3] = (short)f2b(v[3]);
  *(s16x4*)dst = sv;
}

// LayerNorm(256) + classifier (8 outputs). One wave per row.
__global__ __launch_bounds__(256) void final_ln_cls(
    const float* __restrict__ h, const float* __restrict__ g,
    const float* __restrict__ be, const float* __restrict__ Wc,
    const float* __restrict__ bc, float* __restrict__ out) {
  const int wave = threadIdx.x >> 6, lane = threadIdx.x & 63;
  const int row = blockIdx.x * 4 + wave;
  const float4v* hr = (const float4v*)(h + (long)row * 256);
  float4v v = hr[lane];
  float s = v[0] + v[1] + v[2] + v[3];
#pragma unroll
  for (int o = 32; o; o >>= 1) s += __shfl_xor(s, o);
  const float mu = s * (1.f / 256.f);
  float d0 = v[0] - mu, d1 = v[1] - mu, d2 = v[2] - mu, d3 = v[3] - mu;
  float qq = d0 * d0 + d1 * d1 + d2 * d2 + d3 * d3;
#pragma unroll
  for (int o = 32; o; o >>= 1) qq += __shfl_xor(qq, o);
  const float rs = rsqrtf(qq * (1.f / 256.f) + 1e-5f);
  const float4v gv = ((const float4v*)g)[lane];
  const float4v bv = ((const float4v*)be)[lane];
  float hn[4];
  hn[0] = d0 * rs * gv[0] + bv[0];
  hn[1] = d1 * rs * gv[1] + bv[1];
  hn[2] = d2 * rs * gv[2] + bv[2];
  hn[3] = d3 * rs * gv[3] + bv[3];
  float lg[8];
#pragma unroll
  for (int o = 0; o < 8; ++o) {
    const float4v wv = ((const float4v*)(Wc + o * 256))[lane];
    float p = hn[0] * wv[0] + hn[1] * wv[1] + hn[2] * wv[2] + hn[3] * wv[3];
#pragma unroll
    for (int x = 32; x; x >>= 1) p += __shfl_xor(p, x);
    lg[o] = p;
  }
  if (lane == 0) {
#pragma unroll
    for (int o = 0; o < 8; ++o) out[(long)row * 8 + o] = lg[o] + bc[o];
  }
}

extern "C" void kernel_launch(void* const* d_in, const int* in_sizes, int n_in,
                              void* d_out, int out_size, void* d_ws,
                              size_t ws_size, hipStream_t stream) {
  const float* x      = (const float*)d_in[0];
  const float* W_pre  = (const float*)d_in[1];
  const float* b_pre  = (const float*)d_in[2];
  const float* in_w   = (const float*)d_in[3];
  const float* conv_w = (const float*)d_in[4];
  const float* conv_b = (const float*)d_in[5];
  const float* x_w    = (const float*)d_in[6];
  const float* dt_w   = (const float*)d_in[7];
  const float* dt_b   = (const float*)d_in[8];
  // d_in[9] = A_log: dead (scan starts from h0=0 and L=1)
  const float* Dp     = (const float*)d_in[10];
  const float* out_w  = (const float*)d_in[11];
  const float* ln_g   = (const float*)d_in[12];
  const float* ln_b   = (const float*)d_in[13];
  const float* W_cls  = (const float*)d_in[14];
  const float* b_cls  = (const float*)d_in[15];
  float* out = (float*)d_out;

  char* w = (char*)d_ws;
  unsigned short* wpreb = (unsigned short*)w; w += 256 * 2048 * 2;
  unsigned short* inwb  = (unsigned short*)w; w += 5 * 1024 * 256 * 2;
  unsigned short* xwpb  = (unsigned short*)w; w += 5 * 64 * 512 * 2;
  unsigned short* owb   = (unsigned short*)w; w += 5 * 256 * 512 * 2;
  unsigned short* dtwpb = (unsigned short*)w; w += 5 * 512 * 32 * 2;
  float*          h     = (float*)w;          w += 8192 * 256 * 4;
  unsigned short* hb    = (unsigned short*)w; w += 8192 * 256 * 2;
  unsigned short* xb    = (unsigned short*)w; w += 8192 * 2048 * 2;

  precast<<<2672, 256, 0, stream>>>(W_pre, in_w, out_w, x_w, dt_w, conv_w,
                                    wpreb, inwb, owb, xwpb, dtwpb);
  castx<<<2048, 256, 0, stream>>>(x, xb);

  // h = x @ W_pre^T + b_pre  (fp32 of + bf16 ob)
  gemm_pl<128, 64><<<256, 256, 0, stream>>>(
      xb, wpreb, 256, 2048, 4, b_pre, h, hb);

  // all 5 Mamba blocks, one persistent kernel, h resident
  mamba5<<<256, 512, 0, stream>>>(hb, h, inwb, xwpb, dtwpb, owb,
                                  conv_b, dt_b, Dp, h);

  final_ln_cls<<<2048, 256, 0, stream>>>(h, ln_g, ln_b, W_cls, b_cls, out);
}